// Round 2
// baseline (9066.557 us; speedup 1.0000x reference)
//
#include <hip/hip_runtime.h>
#include <hip/hip_bf16.h>

#define DIM 1024
#define NH 16
#define DH 64
#define HID 4096
#define T0TOK 5480   // 4 * 1370
#define N0TOK 1370
#define N1TOK 257
#define TTOT 7536    // 5480 + 2056
#define LN_EPS 1e-5f

typedef __hip_bfloat16 bf16;
typedef __bf16 bf16x8 __attribute__((ext_vector_type(8)));
typedef float f32x4 __attribute__((ext_vector_type(4)));

static __device__ __forceinline__ ushort f2bf(float v) {
  return __hip_bfloat16_raw(__float2bfloat16(v)).x;
}
static __device__ __forceinline__ float bf2f(ushort u) {
  return __uint_as_float(((unsigned int)u) << 16);
}

// ---------------------------------------------------------------- transpose+cvt
// WT[n][k] = bf16(W[k][n]).  W: K x N row-major fp32. K,N % 32 == 0.
__global__ __launch_bounds__(256) void transpose_cvt_kernel(
    const float* __restrict__ W, ushort* __restrict__ WT, int K, int N) {
  __shared__ ushort tile[32][33];
  const int tx = threadIdx.x & 31;
  const int ty = threadIdx.x >> 5;           // 0..7
  const int n0 = blockIdx.x * 32, k0 = blockIdx.y * 32;
#pragma unroll
  for (int i = 0; i < 32; i += 8)
    tile[ty + i][tx] = f2bf(W[(size_t)(k0 + ty + i) * N + n0 + tx]);
  __syncthreads();
#pragma unroll
  for (int i = 0; i < 32; i += 8)
    WT[(size_t)(n0 + ty + i) * K + k0 + tx] = tile[tx][ty + i];
}

// ---------------------------------------------------------------- layernorm
// One block per token row of 1024. fp32 in (split across two tensors at rowsA),
// bf16 out.
__global__ __launch_bounds__(256) void ln_kernel(
    const float* __restrict__ srcA, const float* __restrict__ srcB, int rowsA,
    const float* __restrict__ g, const float* __restrict__ b,
    ushort* __restrict__ out) {
  const int row = blockIdx.x;
  const float* src = (row < rowsA) ? (srcA + (size_t)row * DIM)
                                   : (srcB + (size_t)(row - rowsA) * DIM);
  const int tid = threadIdx.x;
  float4 xv = *(const float4*)(src + tid * 4);
  float x[4] = {xv.x, xv.y, xv.z, xv.w};
  float s1 = x[0] + x[1] + x[2] + x[3];
  float s2 = x[0]*x[0] + x[1]*x[1] + x[2]*x[2] + x[3]*x[3];
#pragma unroll
  for (int off = 32; off; off >>= 1) {
    s1 += __shfl_xor(s1, off);
    s2 += __shfl_xor(s2, off);
  }
  __shared__ float as1[4], as2[4];
  const int wave = tid >> 6, lane = tid & 63;
  if (lane == 0) { as1[wave] = s1; as2[wave] = s2; }
  __syncthreads();
  s1 = as1[0] + as1[1] + as1[2] + as1[3];
  s2 = as2[0] + as2[1] + as2[2] + as2[3];
  const float mean = s1 * (1.0f / DIM);
  const float var = s2 * (1.0f / DIM) - mean * mean;
  const float rstd = rsqrtf(var + LN_EPS);
  float4 gv = *(const float4*)(g + tid * 4);
  float4 bv = *(const float4*)(b + tid * 4);
  float gg[4] = {gv.x, gv.y, gv.z, gv.w};
  float bb[4] = {bv.x, bv.y, bv.z, bv.w};
  union { ushort4 u4; ushort us[4]; } uo;
#pragma unroll
  for (int k = 0; k < 4; ++k)
    uo.us[k] = f2bf((x[k] - mean) * rstd * gg[k] + bb[k]);
  *(ushort4*)(out + (size_t)row * DIM + tid * 4) = uo.u4;
}

// ---------------------------------------------------------------- attention
// One wave per (head, query). lane = dh index. Online softmax over the
// query's own sample's keys. qkv rows: [3][NH][DH] = 3072 bf16 per token.
__global__ __launch_bounds__(256) void attn_kernel(
    const ushort* __restrict__ qkv, ushort* __restrict__ out) {
  const int wid = blockIdx.x * 4 + (threadIdx.x >> 6);
  const int lane = threadIdx.x & 63;
  const int head = wid / TTOT;
  const int q = wid - head * TTOT;
  int start, n;
  if (q < T0TOK) { int s = q / N0TOK; start = s * N0TOK; n = N0TOK; }
  else { int qq = q - T0TOK; int s = qq / N1TOK; start = T0TOK + s * N1TOK; n = N1TOK; }
  const size_t hoff = (size_t)head * DH + lane;
  const float qv = bf2f(qkv[(size_t)q * (3 * DIM) + hoff]) * 0.125f; // dh^-0.5
  const ushort* kp = qkv + DIM + hoff;
  const ushort* vp = qkv + 2 * DIM + hoff;
  float m = -1e30f, l = 0.f, acc = 0.f;
  for (int j = start; j < start + n; ++j) {
    float s = qv * bf2f(kp[(size_t)j * (3 * DIM)]);
#pragma unroll
    for (int off = 32; off; off >>= 1) s += __shfl_xor(s, off);
    float mn = fmaxf(m, s);
    float alpha = __expf(m - mn);
    float p = __expf(s - mn);
    float vd = bf2f(vp[(size_t)j * (3 * DIM)]);
    l = l * alpha + p;
    acc = acc * alpha + p * vd;
    m = mn;
  }
  out[(size_t)q * DIM + hoff] = f2bf(acc / l);
}

// ---------------------------------------------------------------- GEMM
// C[M,N] = A[M,K] @ W[K,N] (+bias, +epilogue). WT is W transposed: N x K (bf16).
// A is bf16. bias/res/ls fp32. 128x128 tile / block (256 thr, 4 waves 2x2 of
// 64x64), BK=32, mfma_f32_16x16x32_bf16. A-frag: [m=lane&15][k=quad*8+j];
// B-frag: [n=lane&15][k=quad*8+j] (WT rows); D: col=lane&15, row=quad*4+r.
// EPI_BIAS/EPI_GELU write bf16; EPI_RESID writes fp32 (res + ls*val).
#define EPI_BIAS 0
#define EPI_RESID 1
#define EPI_GELU 2

template <int EPI>
__global__ __launch_bounds__(256) void gemm_kernel(
    const ushort* __restrict__ A, const ushort* __restrict__ WT,
    const float* __restrict__ bias, void* __restrict__ outv,
    int M, int N, int K,
    const float* __restrict__ resA, const float* __restrict__ resB,
    const float* __restrict__ ls, int rowsA) {
  __shared__ ushort As[128 * 40];  // [row m][k 32 + pad 8]
  __shared__ ushort Bs[128 * 40];  // [row n][k 32 + pad 8]
  const int tid = threadIdx.x;
  const int wave = tid >> 6, lane = tid & 63;
  const int quad = lane >> 4, l16 = lane & 15;
  const int m0 = blockIdx.y * 128, n0 = blockIdx.x * 128;
  const int wm = (wave >> 1) * 64, wn = (wave & 1) * 64;
  f32x4 acc[4][4];
#pragma unroll
  for (int i = 0; i < 4; ++i)
#pragma unroll
    for (int j = 0; j < 4; ++j) acc[i][j] = (f32x4){0.f, 0.f, 0.f, 0.f};

  for (int k0 = 0; k0 < K; k0 += 32) {
#pragma unroll
    for (int it = 0; it < 2; ++it) {
      const int c = tid + it * 256;         // 512 chunks of 8 bf16
      const int row = c >> 2, kc = c & 3;
      const int gcol = k0 + kc * 8;
      uint4 vb = *(const uint4*)(WT + (size_t)(n0 + row) * K + gcol);
      uint4 va = {0u, 0u, 0u, 0u};
      const int ar = m0 + row;
      if (ar < M) va = *(const uint4*)(A + (size_t)ar * K + gcol);
      *(uint4*)(&As[row * 40 + kc * 8]) = va;
      *(uint4*)(&Bs[row * 40 + kc * 8]) = vb;
    }
    __syncthreads();
    bf16x8 af[4], bfr[4];
#pragma unroll
    for (int i = 0; i < 4; ++i)
      af[i] = *reinterpret_cast<const bf16x8*>(&As[(wm + i * 16 + l16) * 40 + quad * 8]);
#pragma unroll
    for (int j = 0; j < 4; ++j)
      bfr[j] = *reinterpret_cast<const bf16x8*>(&Bs[(wn + j * 16 + l16) * 40 + quad * 8]);
#pragma unroll
    for (int i = 0; i < 4; ++i)
#pragma unroll
      for (int j = 0; j < 4; ++j)
        acc[i][j] = __builtin_amdgcn_mfma_f32_16x16x32_bf16(af[i], bfr[j], acc[i][j], 0, 0, 0);
    __syncthreads();
  }

#pragma unroll
  for (int j = 0; j < 4; ++j) {
    const int col = n0 + wn + j * 16 + l16;
    const float bj = bias[col];
    float lsj = 0.f;
    if (EPI == EPI_RESID) lsj = ls[col];
#pragma unroll
    for (int i = 0; i < 4; ++i) {
#pragma unroll
      for (int r = 0; r < 4; ++r) {
        const int row = m0 + wm + i * 16 + quad * 4 + r;
        if (row < M) {
          float v = acc[i][j][r] + bj;
          if (EPI == EPI_GELU) v = 0.5f * v * (1.0f + erff(v * 0.70710678f));
          if (EPI == EPI_RESID) {
            const float* res = (row < rowsA) ? (resA + (size_t)row * N)
                                             : (resB + (size_t)(row - rowsA) * N);
            ((float*)outv)[(size_t)row * N + col] = res[col] + lsj * v;
          } else {
            ((ushort*)outv)[(size_t)row * N + col] = f2bf(v);
          }
        }
      }
    }
  }
}

// ---------------------------------------------------------------- launch
extern "C" void kernel_launch(void* const* d_in, const int* in_sizes, int n_in,
                              void* d_out, int out_size, void* d_ws, size_t ws_size,
                              hipStream_t stream) {
  const float* x0     = (const float*)d_in[0];
  const float* x1     = (const float*)d_in[1];
  const float* ln1_g  = (const float*)d_in[2];
  const float* ln1_b  = (const float*)d_in[3];
  const float* qkv_w  = (const float*)d_in[4];
  const float* qkv_b  = (const float*)d_in[5];
  const float* proj_w = (const float*)d_in[6];
  const float* proj_b = (const float*)d_in[7];
  const float* ls1    = (const float*)d_in[8];
  const float* ln2_g  = (const float*)d_in[9];
  const float* ln2_b  = (const float*)d_in[10];
  const float* fc1_w  = (const float*)d_in[11];
  const float* fc1_b  = (const float*)d_in[12];
  const float* fc2_w  = (const float*)d_in[13];
  const float* fc2_b  = (const float*)d_in[14];
  const float* ls2    = (const float*)d_in[15];
  float* out = (float*)d_out;

  // workspace layout: fp32 h buffer first, then bf16 buffers
  float* hbuf = (float*)d_ws;                                  // TTOT*DIM fp32
  ushort* wt_qkv  = (ushort*)(hbuf + (size_t)TTOT * DIM);
  ushort* wt_proj = wt_qkv  + (size_t)3072 * 1024;
  ushort* wt_fc1  = wt_proj + (size_t)1024 * 1024;
  ushort* wt_fc2  = wt_fc1  + (size_t)1024 * 4096;
  ushort* lnbuf   = wt_fc2  + (size_t)4096 * 1024;             // TTOT*DIM bf16
  ushort* attnbuf = lnbuf   + (size_t)TTOT * DIM;              // TTOT*DIM bf16
  ushort* bigbuf  = attnbuf + (size_t)TTOT * DIM;              // TTOT*4096 bf16

  const dim3 b256(256);
  const int mblk = (TTOT + 127) / 128;  // 59

  transpose_cvt_kernel<<<dim3(3072 / 32, 1024 / 32), b256, 0, stream>>>(
      qkv_w, wt_qkv, 1024, 3072);
  transpose_cvt_kernel<<<dim3(1024 / 32, 1024 / 32), b256, 0, stream>>>(
      proj_w, wt_proj, 1024, 1024);
  transpose_cvt_kernel<<<dim3(4096 / 32, 1024 / 32), b256, 0, stream>>>(
      fc1_w, wt_fc1, 1024, 4096);
  transpose_cvt_kernel<<<dim3(1024 / 32, 4096 / 32), b256, 0, stream>>>(
      fc2_w, wt_fc2, 4096, 1024);

  ln_kernel<<<TTOT, b256, 0, stream>>>(x0, x1, T0TOK, ln1_g, ln1_b, lnbuf);

  gemm_kernel<EPI_BIAS><<<dim3(3072 / 128, mblk), b256, 0, stream>>>(
      lnbuf, wt_qkv, qkv_b, bigbuf, TTOT, 3072, 1024, nullptr, nullptr, nullptr, 0);

  attn_kernel<<<(TTOT * NH) / 4, b256, 0, stream>>>(bigbuf, attnbuf);

  gemm_kernel<EPI_RESID><<<dim3(1024 / 128, mblk), b256, 0, stream>>>(
      attnbuf, wt_proj, proj_b, hbuf, TTOT, 1024, 1024, x0, x1, ls1, T0TOK);

  ln_kernel<<<TTOT, b256, 0, stream>>>(hbuf, hbuf + (size_t)T0TOK * DIM, T0TOK,
                                       ln2_g, ln2_b, lnbuf);

  gemm_kernel<EPI_GELU><<<dim3(4096 / 128, mblk), b256, 0, stream>>>(
      lnbuf, wt_fc1, fc1_b, bigbuf, TTOT, 4096, 1024, nullptr, nullptr, nullptr, 0);

  gemm_kernel<EPI_RESID><<<dim3(1024 / 128, mblk), b256, 0, stream>>>(
      bigbuf, wt_fc2, fc2_b, out, TTOT, 1024, 4096, hbuf,
      hbuf + (size_t)T0TOK * DIM, ls2, T0TOK);
}

// Round 3
// 808.913 us; speedup vs baseline: 11.2083x; 11.2083x over previous
//
#include <hip/hip_runtime.h>
#include <hip/hip_bf16.h>

#define DIM 1024
#define NH 16
#define DH 64
#define HID 4096
#define T0TOK 5480   // 4 * 1370
#define N0TOK 1370
#define N1TOK 257
#define TTOT 7536    // 5480 + 2056
#define LN_EPS 1e-5f
#define VTCOLS 7808  // 4*1376 + 8*288 (per-sample padded token columns)

typedef __hip_bfloat16 bf16;
typedef __bf16 bf16x8 __attribute__((ext_vector_type(8)));
typedef float f32x4 __attribute__((ext_vector_type(4)));

static __device__ __forceinline__ ushort f2bf(float v) {
  return __hip_bfloat16_raw(__float2bfloat16(v)).x;
}
static __device__ __forceinline__ float bf2f(ushort u) {
  return __uint_as_float(((unsigned int)u) << 16);
}

// ---------------------------------------------------------------- transpose+cvt
__global__ __launch_bounds__(256) void transpose_cvt_kernel(
    const float* __restrict__ W, ushort* __restrict__ WT, int K, int N) {
  __shared__ ushort tile[32][33];
  const int tx = threadIdx.x & 31;
  const int ty = threadIdx.x >> 5;
  const int n0 = blockIdx.x * 32, k0 = blockIdx.y * 32;
#pragma unroll
  for (int i = 0; i < 32; i += 8)
    tile[ty + i][tx] = f2bf(W[(size_t)(k0 + ty + i) * N + n0 + tx]);
  __syncthreads();
#pragma unroll
  for (int i = 0; i < 32; i += 8)
    WT[(size_t)(n0 + ty + i) * K + k0 + tx] = tile[tx][ty + i];
}

// ---------------------------------------------------------------- layernorm
__global__ __launch_bounds__(256) void ln_kernel(
    const float* __restrict__ srcA, const float* __restrict__ srcB, int rowsA,
    const float* __restrict__ g, const float* __restrict__ b,
    ushort* __restrict__ out) {
  const int row = blockIdx.x;
  const float* src = (row < rowsA) ? (srcA + (size_t)row * DIM)
                                   : (srcB + (size_t)(row - rowsA) * DIM);
  const int tid = threadIdx.x;
  float4 xv = *(const float4*)(src + tid * 4);
  float x[4] = {xv.x, xv.y, xv.z, xv.w};
  float s1 = x[0] + x[1] + x[2] + x[3];
  float s2 = x[0]*x[0] + x[1]*x[1] + x[2]*x[2] + x[3]*x[3];
#pragma unroll
  for (int off = 32; off; off >>= 1) {
    s1 += __shfl_xor(s1, off);
    s2 += __shfl_xor(s2, off);
  }
  __shared__ float as1[4], as2[4];
  const int wave = tid >> 6, lane = tid & 63;
  if (lane == 0) { as1[wave] = s1; as2[wave] = s2; }
  __syncthreads();
  s1 = as1[0] + as1[1] + as1[2] + as1[3];
  s2 = as2[0] + as2[1] + as2[2] + as2[3];
  const float mean = s1 * (1.0f / DIM);
  const float var = s2 * (1.0f / DIM) - mean * mean;
  const float rstd = rsqrtf(var + LN_EPS);
  float4 gv = *(const float4*)(g + tid * 4);
  float4 bv = *(const float4*)(b + tid * 4);
  float gg[4] = {gv.x, gv.y, gv.z, gv.w};
  float bb[4] = {bv.x, bv.y, bv.z, bv.w};
  union { ushort4 u4; ushort us[4]; } uo;
#pragma unroll
  for (int k = 0; k < 4; ++k)
    uo.us[k] = f2bf((x[k] - mean) * rstd * gg[k] + bb[k]);
  *(ushort4*)(out + (size_t)row * DIM + tid * 4) = uo.u4;
}

// ---------------------------------------------------------------- flash attn
// Block = (head, 64-query tile within one sample). 4 waves x 16 queries.
// Per 32-key tile: S = Q K^T via 4 mfma_16x16x32; online softmax (stats
// amortized over 32 keys); P via per-wave LDS (C-layout -> A-layout); PV via
// 4 mfma from LDS-staged Vt tile. Q pre-scaled by 0.125 in qkv epilogue.
__global__ __launch_bounds__(256) void fattn_kernel(
    const ushort* __restrict__ Qb, const ushort* __restrict__ Kb,
    const ushort* __restrict__ Vt, ushort* __restrict__ out) {
  __shared__ ushort Ks[32 * 72];       // [key][dh], stride 72
  __shared__ ushort Vs[64 * 40];       // [d][key], stride 40
  __shared__ ushort Ps[4][16 * 40];    // per-wave [q][key], stride 40

  const int b = blockIdx.x;
  const int head = b >> 7;             // 128 (seg,qtile) combos per head
  const int st = b & 127;
  int seg_start, nk, qt, vbase;
  if (st < 88) {
    int s = st / 22; qt = st % 22;
    seg_start = s * N0TOK; nk = N0TOK; vbase = s * 1376;
  } else {
    int u = st - 88; int s = u / 5; qt = u % 5;
    seg_start = T0TOK + s * N1TOK; nk = N1TOK; vbase = 5504 + s * 288;
  }
  const int qbase = qt * 64;           // local query base
  const int tid = threadIdx.x;
  const int wv = tid >> 6, lane = tid & 63;
  const int quad = lane >> 4, l16 = lane & 15;
  const int h64 = head * DH;

  // Q fragments (A-layout: m=l16 query, k=quad*8+j dh)
  int qloc = qbase + wv * 16 + l16; if (qloc >= nk) qloc = nk - 1;
  const ushort* qrow = Qb + (size_t)(seg_start + qloc) * DIM + h64 + quad * 8;
  const bf16x8 qf0 = *(const bf16x8*)(qrow);
  const bf16x8 qf1 = *(const bf16x8*)(qrow + 32);

  f32x4 of[4];
#pragma unroll
  for (int c = 0; c < 4; ++c) of[c] = (f32x4){0.f, 0.f, 0.f, 0.f};
  float m[4] = {-1e30f, -1e30f, -1e30f, -1e30f};
  float l[4] = {0.f, 0.f, 0.f, 0.f};

  const int ntiles = (nk + 31) >> 5;
  const int skey = tid >> 3, sd8 = tid & 7;    // K staging map
  const int svd = tid >> 2, svk8 = tid & 3;    // Vt staging map
  for (int t = 0; t < ntiles; ++t) {
    const int kt = t * 32;
    __syncthreads();
    {
      int kg = kt + skey; if (kg >= nk) kg = nk - 1;
      *(uint4*)&Ks[skey * 72 + sd8 * 8] =
          *(const uint4*)(Kb + (size_t)(seg_start + kg) * DIM + h64 + sd8 * 8);
      *(uint4*)&Vs[svd * 40 + svk8 * 8] =
          *(const uint4*)(Vt + (size_t)(h64 + svd) * VTCOLS + vbase + kt + svk8 * 8);
    }
    __syncthreads();

    // S tiles: c=0,1 cover keys kt+c*16+l16
    f32x4 s[2];
#pragma unroll
    for (int c = 0; c < 2; ++c) {
      const ushort* kp = &Ks[(c * 16 + l16) * 72 + quad * 8];
      bf16x8 kf0 = *(const bf16x8*)(kp);
      bf16x8 kf1 = *(const bf16x8*)(kp + 32);
      f32x4 a = (f32x4){0.f, 0.f, 0.f, 0.f};
      a = __builtin_amdgcn_mfma_f32_16x16x32_bf16(qf0, kf0, a, 0, 0, 0);
      a = __builtin_amdgcn_mfma_f32_16x16x32_bf16(qf1, kf1, a, 0, 0, 0);
      s[c] = a;
    }
    const bool v0 = (kt + l16) < nk;
    const bool v1 = (kt + 16 + l16) < nk;
    float alpha[4], p0[4], p1[4];
#pragma unroll
    for (int r = 0; r < 4; ++r) {
      float s0 = v0 ? s[0][r] : -1e30f;
      float s1 = v1 ? s[1][r] : -1e30f;
      float mx = fmaxf(s0, s1);
#pragma unroll
      for (int off = 1; off < 16; off <<= 1) mx = fmaxf(mx, __shfl_xor(mx, off));
      float mnew = fmaxf(m[r], mx);
      alpha[r] = __expf(m[r] - mnew);
      p0[r] = __expf(s0 - mnew);
      p1[r] = __expf(s1 - mnew);
      float ps = p0[r] + p1[r];
#pragma unroll
      for (int off = 1; off < 16; off <<= 1) ps += __shfl_xor(ps, off);
      l[r] = l[r] * alpha[r] + ps;
      m[r] = mnew;
    }
    // P: C-layout -> LDS [q][key] -> A-layout fragment
#pragma unroll
    for (int r = 0; r < 4; ++r) {
      Ps[wv][(quad * 4 + r) * 40 + l16] = f2bf(p0[r]);
      Ps[wv][(quad * 4 + r) * 40 + 16 + l16] = f2bf(p1[r]);
    }
#pragma unroll
    for (int c = 0; c < 4; ++c)
#pragma unroll
      for (int r = 0; r < 4; ++r) of[c][r] *= alpha[r];
    bf16x8 pf = *(const bf16x8*)&Ps[wv][l16 * 40 + quad * 8];
#pragma unroll
    for (int c = 0; c < 4; ++c) {
      bf16x8 vf = *(const bf16x8*)&Vs[(c * 16 + l16) * 40 + quad * 8];
      of[c] = __builtin_amdgcn_mfma_f32_16x16x32_bf16(pf, vf, of[c], 0, 0, 0);
    }
  }

#pragma unroll
  for (int r = 0; r < 4; ++r) {
    const int qr = qbase + wv * 16 + quad * 4 + r;
    if (qr < nk) {
      const float inv = 1.0f / l[r];
      ushort* orow = out + (size_t)(seg_start + qr) * DIM + h64 + l16;
#pragma unroll
      for (int c = 0; c < 4; ++c) orow[c * 16] = f2bf(of[c][r] * inv);
    }
  }
}

// ---------------------------------------------------------------- GEMM
#define EPI_QKV 0
#define EPI_RESID 1
#define EPI_GELU 2

template <int EPI>
__global__ __launch_bounds__(256) void gemm_kernel(
    const ushort* __restrict__ A, const ushort* __restrict__ WT,
    const float* __restrict__ bias, void* __restrict__ outv,
    int M, int N, int K,
    const float* __restrict__ resA, const float* __restrict__ resB,
    const float* __restrict__ ls, int rowsA,
    ushort* __restrict__ outK, ushort* __restrict__ outVt) {
  __shared__ ushort As[128 * 40];
  __shared__ ushort Bs[128 * 40];
  const int tid = threadIdx.x;
  const int wave = tid >> 6, lane = tid & 63;
  const int quad = lane >> 4, l16 = lane & 15;
  const int m0 = blockIdx.y * 128, n0 = blockIdx.x * 128;
  const int wm = (wave >> 1) * 64, wn = (wave & 1) * 64;
  f32x4 acc[4][4];
#pragma unroll
  for (int i = 0; i < 4; ++i)
#pragma unroll
    for (int j = 0; j < 4; ++j) acc[i][j] = (f32x4){0.f, 0.f, 0.f, 0.f};

  for (int k0 = 0; k0 < K; k0 += 32) {
#pragma unroll
    for (int it = 0; it < 2; ++it) {
      const int c = tid + it * 256;
      const int row = c >> 2, kc = c & 3;
      const int gcol = k0 + kc * 8;
      uint4 vb = *(const uint4*)(WT + (size_t)(n0 + row) * K + gcol);
      uint4 va = {0u, 0u, 0u, 0u};
      const int ar = m0 + row;
      if (ar < M) va = *(const uint4*)(A + (size_t)ar * K + gcol);
      *(uint4*)(&As[row * 40 + kc * 8]) = va;
      *(uint4*)(&Bs[row * 40 + kc * 8]) = vb;
    }
    __syncthreads();
    bf16x8 af[4], bfr[4];
#pragma unroll
    for (int i = 0; i < 4; ++i)
      af[i] = *reinterpret_cast<const bf16x8*>(&As[(wm + i * 16 + l16) * 40 + quad * 8]);
#pragma unroll
    for (int j = 0; j < 4; ++j)
      bfr[j] = *reinterpret_cast<const bf16x8*>(&Bs[(wn + j * 16 + l16) * 40 + quad * 8]);
#pragma unroll
    for (int i = 0; i < 4; ++i)
#pragma unroll
      for (int j = 0; j < 4; ++j)
        acc[i][j] = __builtin_amdgcn_mfma_f32_16x16x32_bf16(af[i], bfr[j], acc[i][j], 0, 0, 0);
    __syncthreads();
  }

#pragma unroll
  for (int j = 0; j < 4; ++j) {
    const int col = n0 + wn + j * 16 + l16;
    const float bj = bias[col];
    float lsj = 0.f;
    if (EPI == EPI_RESID) lsj = ls[col];
#pragma unroll
    for (int i = 0; i < 4; ++i) {
#pragma unroll
      for (int r = 0; r < 4; ++r) {
        const int row = m0 + wm + i * 16 + quad * 4 + r;
        if (row < M) {
          float v = acc[i][j][r] + bj;
          if (EPI == EPI_GELU) {
            v = 0.5f * v * (1.0f + erff(v * 0.70710678f));
            ((ushort*)outv)[(size_t)row * N + col] = f2bf(v);
          } else if (EPI == EPI_RESID) {
            const float* res = (row < rowsA) ? (resA + (size_t)row * N)
                                             : (resB + (size_t)(row - rowsA) * N);
            ((float*)outv)[(size_t)row * N + col] = res[col] + lsj * v;
          } else {  // EPI_QKV: split into Q (scaled), K, V^T (padded cols)
            if (col < DIM) {
              ((ushort*)outv)[(size_t)row * DIM + col] = f2bf(v * 0.125f);
            } else if (col < 2 * DIM) {
              outK[(size_t)row * DIM + (col - DIM)] = f2bf(v);
            } else {
              const int vrow = col - 2 * DIM;  // head*64 + d
              int vcol;
              if (row < T0TOK) {
                int s = row / N0TOK;
                vcol = s * 1376 + (row - s * N0TOK);
              } else {
                int rr = row - T0TOK;
                int s = rr / N1TOK;
                vcol = 5504 + s * 288 + (rr - s * N1TOK);
              }
              outVt[(size_t)vrow * VTCOLS + vcol] = f2bf(v);
            }
          }
        }
      }
    }
  }
}

// ---------------------------------------------------------------- launch
extern "C" void kernel_launch(void* const* d_in, const int* in_sizes, int n_in,
                              void* d_out, int out_size, void* d_ws, size_t ws_size,
                              hipStream_t stream) {
  const float* x0     = (const float*)d_in[0];
  const float* x1     = (const float*)d_in[1];
  const float* ln1_g  = (const float*)d_in[2];
  const float* ln1_b  = (const float*)d_in[3];
  const float* qkv_w  = (const float*)d_in[4];
  const float* qkv_b  = (const float*)d_in[5];
  const float* proj_w = (const float*)d_in[6];
  const float* proj_b = (const float*)d_in[7];
  const float* ls1    = (const float*)d_in[8];
  const float* ln2_g  = (const float*)d_in[9];
  const float* ln2_b  = (const float*)d_in[10];
  const float* fc1_w  = (const float*)d_in[11];
  const float* fc1_b  = (const float*)d_in[12];
  const float* fc2_w  = (const float*)d_in[13];
  const float* fc2_b  = (const float*)d_in[14];
  const float* ls2    = (const float*)d_in[15];
  float* out = (float*)d_out;

  float* hbuf = (float*)d_ws;                                  // TTOT*DIM fp32
  ushort* wt_qkv  = (ushort*)(hbuf + (size_t)TTOT * DIM);
  ushort* wt_proj = wt_qkv  + (size_t)3072 * 1024;
  ushort* wt_fc1  = wt_proj + (size_t)1024 * 1024;
  ushort* wt_fc2  = wt_fc1  + (size_t)1024 * 4096;
  ushort* lnbuf   = wt_fc2  + (size_t)4096 * 1024;             // TTOT*DIM bf16
  ushort* attnbuf = lnbuf   + (size_t)TTOT * DIM;              // TTOT*DIM bf16
  ushort* bigbuf  = attnbuf + (size_t)TTOT * DIM;              // TTOT*HID bf16
  // Q/K/Vt alias the (later-used) fc1 buffer: 2*TTOT*DIM + 1024*VTCOLS < TTOT*HID
  ushort* qbuf = bigbuf;
  ushort* kbuf = bigbuf + (size_t)TTOT * DIM;
  ushort* vtbuf = bigbuf + (size_t)2 * TTOT * DIM;

  const dim3 b256(256);
  const int mblk = (TTOT + 127) / 128;  // 59

  transpose_cvt_kernel<<<dim3(3072 / 32, 1024 / 32), b256, 0, stream>>>(
      qkv_w, wt_qkv, 1024, 3072);
  transpose_cvt_kernel<<<dim3(1024 / 32, 1024 / 32), b256, 0, stream>>>(
      proj_w, wt_proj, 1024, 1024);
  transpose_cvt_kernel<<<dim3(4096 / 32, 1024 / 32), b256, 0, stream>>>(
      fc1_w, wt_fc1, 1024, 4096);
  transpose_cvt_kernel<<<dim3(1024 / 32, 4096 / 32), b256, 0, stream>>>(
      fc2_w, wt_fc2, 4096, 1024);

  ln_kernel<<<TTOT, b256, 0, stream>>>(x0, x1, T0TOK, ln1_g, ln1_b, lnbuf);

  gemm_kernel<EPI_QKV><<<dim3(3072 / 128, mblk), b256, 0, stream>>>(
      lnbuf, wt_qkv, qkv_b, qbuf, TTOT, 3072, 1024, nullptr, nullptr, nullptr, 0,
      kbuf, vtbuf);

  fattn_kernel<<<NH * 128, b256, 0, stream>>>(qbuf, kbuf, vtbuf, attnbuf);

  gemm_kernel<EPI_RESID><<<dim3(1024 / 128, mblk), b256, 0, stream>>>(
      attnbuf, wt_proj, proj_b, hbuf, TTOT, 1024, 1024, x0, x1, ls1, T0TOK,
      nullptr, nullptr);

  ln_kernel<<<TTOT, b256, 0, stream>>>(hbuf, hbuf + (size_t)T0TOK * DIM, T0TOK,
                                       ln2_g, ln2_b, lnbuf);

  gemm_kernel<EPI_GELU><<<dim3(4096 / 128, mblk), b256, 0, stream>>>(
      lnbuf, wt_fc1, fc1_b, bigbuf, TTOT, 4096, 1024, nullptr, nullptr, nullptr, 0,
      nullptr, nullptr);

  gemm_kernel<EPI_RESID><<<dim3(1024 / 128, mblk), b256, 0, stream>>>(
      bigbuf, wt_fc2, fc2_b, out, TTOT, 1024, 4096, hbuf,
      hbuf + (size_t)T0TOK * DIM, ls2, T0TOK, nullptr, nullptr);
}